// Round 5
// baseline (49.168 us; speedup 1.0000x reference)
//
#include <hip/hip_runtime.h>
#include <hip/hip_bf16.h>

typedef __attribute__((ext_vector_type(8))) short short8;   // 8 bf16 MFMA A/B frag
typedef __attribute__((ext_vector_type(4))) float fv4;      // MFMA C/D frag

constexpr int B_ = 16, A_ = 1024, V_ = 1024, D_ = 512;

__device__ __forceinline__ unsigned cvtpk(float lo, float hi) {
    unsigned r;
    asm("v_cvt_pk_bf16_f32 %0, %1, %2" : "=v"(r) : "v"(lo), "v"(hi));
    return r;
}
#define SB0() __builtin_amdgcn_sched_barrier(0)

struct Stage { fv4 x0, x1, x2, x3; };

// Fused: fp32 -> bf16 convert + row norms + 256x256 MFMA tile + sqrt epilogue.
// 512 threads = 8 waves (2M x 4N). BK=64, 8 K-tiles, double-buffered LDS.
// Loads for tile kt+1's staging are issued one tile-boundary EARLY (cross-
// barrier prefetch); norms accumulate in registers, reduced once post-loop.
__global__ void __launch_bounds__(512, 2)
l2dist_fused256(const float* __restrict__ audio, const float* __restrict__ visual,
                float* __restrict__ out)
{
    __shared__ __align__(16) char sA[2 * 256 * 128];   // [buf][row 256][64 bf16]
    __shared__ __align__(16) char sB[2 * 256 * 128];
    __shared__ float lnrm[512];                        // [0..255]=A rows, [256..511]=V rows

    const int t = threadIdx.x, lane = t & 63, w = t >> 6;
    const int wm = w >> 2, wn = w & 3;                 // wave C-slab: 128 rows x 64 cols

    // XCD-bijective swizzle: 256 blocks; each XCD gets 32 = 2 whole batches.
    const int orig = blockIdx.x;
    const int wg   = (orig & 7) * 32 + (orig >> 3);
    const int b = wg >> 4, tile = wg & 15, ab = tile >> 2, vb = tile & 3;

    const float* Ag = audio  + ((size_t)b * A_ + ab * 256) * D_;
    const float* Vg = visual + ((size_t)b * V_ + vb * 256) * D_;

    // staging geometry: 4-lane quad per row; thread covers 16 floats of one row
    const int rg  = t >> 2;            // 0..127 row within half-panel
    const int lq  = t & 3;             // quad lane
    const int key = rg & 7;            // LDS chunk swizzle key

    const float* g0 = Ag + (size_t)rg * D_ + lq * 4;           // A rows 0-127
    const float* g1 = Ag + (size_t)(128 + rg) * D_ + lq * 4;   // A rows 128-255
    const float* g2 = Vg + (size_t)rg * D_ + lq * 4;           // V rows 0-127
    const float* g3 = Vg + (size_t)(128 + rg) * D_ + lq * 4;   // V rows 128-255

    const int oLo = rg * 128;                // LDS row byte offset, half 0
    const int oHi = (128 + rg) * 128;        // half 1

    float ps0 = 0.f, ps1 = 0.f, ps2 = 0.f, ps3 = 0.f;   // register norm partials

#define ISSUE(S, gbase, koff) do {                                   \
        const float* _p = (gbase) + (koff);                          \
        S.x0 = *(const fv4*)(_p);      S.x1 = *(const fv4*)(_p + 16);\
        S.x2 = *(const fv4*)(_p + 32); S.x3 = *(const fv4*)(_p + 48);\
    } while (0)

    // convert + fp32 norm partial + swizzled LDS write for one quarter
#define PROC(S, dst, rowoff, ps) do {                                            \
        ps += S.x0[0]*S.x0[0] + S.x0[1]*S.x0[1] + S.x0[2]*S.x0[2] + S.x0[3]*S.x0[3] \
            + S.x1[0]*S.x1[0] + S.x1[1]*S.x1[1] + S.x1[2]*S.x1[2] + S.x1[3]*S.x1[3] \
            + S.x2[0]*S.x2[0] + S.x2[1]*S.x2[1] + S.x2[2]*S.x2[2] + S.x2[3]*S.x2[3] \
            + S.x3[0]*S.x3[0] + S.x3[1]*S.x3[1] + S.x3[2]*S.x3[2] + S.x3[3]*S.x3[3];\
        char* _d = (dst) + (rowoff);                                             \
        { int2 _v; _v.x = (int)cvtpk(S.x0[0], S.x0[1]); _v.y = (int)cvtpk(S.x0[2], S.x0[3]); \
          *(int2*)(_d + ((((0 + (lq >> 1)) ^ key) << 4) + (lq & 1) * 8)) = _v; } \
        { int2 _v; _v.x = (int)cvtpk(S.x1[0], S.x1[1]); _v.y = (int)cvtpk(S.x1[2], S.x1[3]); \
          *(int2*)(_d + ((((2 + (lq >> 1)) ^ key) << 4) + (lq & 1) * 8)) = _v; } \
        { int2 _v; _v.x = (int)cvtpk(S.x2[0], S.x2[1]); _v.y = (int)cvtpk(S.x2[2], S.x2[3]); \
          *(int2*)(_d + ((((4 + (lq >> 1)) ^ key) << 4) + (lq & 1) * 8)) = _v; } \
        { int2 _v; _v.x = (int)cvtpk(S.x3[0], S.x3[1]); _v.y = (int)cvtpk(S.x3[2], S.x3[3]); \
          *(int2*)(_d + ((((6 + (lq >> 1)) ^ key) << 4) + (lq & 1) * 8)) = _v; } \
    } while (0)

    // ---- prologue: stage K-tile 0 into buf 0; prefetch q0,q1 of K-tile 1 ----
    Stage q0, q1, q2, q3;
    {
        Stage p0, p1, p2, p3;
        ISSUE(p0, g0, 0); ISSUE(p1, g1, 0); ISSUE(p2, g2, 0); ISSUE(p3, g3, 0); SB0();
        PROC(p0, sA, oLo, ps0);
        PROC(p1, sA, oHi, ps1);
        PROC(p2, sB, oLo, ps2);
        PROC(p3, sB, oHi, ps3);
    }
    ISSUE(q0, g0, 64); ISSUE(q1, g1, 64); SB0();   // cross-barrier prefetch
    __syncthreads();

    fv4 acc[8][4];
#pragma unroll
    for (int m = 0; m < 8; ++m)
#pragma unroll
        for (int n = 0; n < 4; ++n) acc[m][n] = fv4{0.f, 0.f, 0.f, 0.f};

    const int frow = lane & 15, fg = lane >> 4, xk = frow & 7;
    const int cof0 = ((0 + fg) ^ xk) << 4;    // k-half 0 swizzled chunk
    const int cof1 = ((4 + fg) ^ xk) << 4;    // k-half 1

#pragma unroll 1
    for (int kt = 0; kt < 8; ++kt) {
        const int cur = kt & 1;
        char* dstA = sA + (cur ^ 1) * 32768;
        char* dstB = sB + (cur ^ 1) * 32768;
        const char* Ab = sA + cur * 32768 + (wm * 128 + frow) * 128;
        const char* Bb = sB + cur * 32768 + (wn * 64 + frow) * 128;
        const int koff = (kt + 1) * 64;       // data staged THIS iteration
        const bool st = (kt < 7);

        short8 av[4][2];
        // ---- phase 0: A m0-3, B n0-1; 16 MFMA ----
        {
            short8 bv[2][2];
#pragma unroll
            for (int m = 0; m < 4; ++m) {
                av[m][0] = *(const short8*)(Ab + m * 2048 + cof0);
                av[m][1] = *(const short8*)(Ab + m * 2048 + cof1);
            }
#pragma unroll
            for (int n = 0; n < 2; ++n) {
                bv[n][0] = *(const short8*)(Bb + n * 2048 + cof0);
                bv[n][1] = *(const short8*)(Bb + n * 2048 + cof1);
            }
            __builtin_amdgcn_s_setprio(1);
#pragma unroll
            for (int k = 0; k < 2; ++k)
#pragma unroll
                for (int m = 0; m < 4; ++m)
#pragma unroll
                    for (int n = 0; n < 2; ++n)
                        acc[m][n] = __builtin_amdgcn_mfma_f32_16x16x32_bf16(av[m][k], bv[n][k], acc[m][n], 0, 0, 0);
            __builtin_amdgcn_s_setprio(0);
        }
        if (st) { PROC(q0, dstA, oLo, ps0); ISSUE(q2, g2, koff); SB0(); }

        // ---- phase 1: B n2-3; 16 MFMA (reuse av) ----
        short8 bv2[2][2];
        {
#pragma unroll
            for (int n = 0; n < 2; ++n) {
                bv2[n][0] = *(const short8*)(Bb + (n + 2) * 2048 + cof0);
                bv2[n][1] = *(const short8*)(Bb + (n + 2) * 2048 + cof1);
            }
            __builtin_amdgcn_s_setprio(1);
#pragma unroll
            for (int k = 0; k < 2; ++k)
#pragma unroll
                for (int m = 0; m < 4; ++m)
#pragma unroll
                    for (int n = 0; n < 2; ++n)
                        acc[m][n + 2] = __builtin_amdgcn_mfma_f32_16x16x32_bf16(av[m][k], bv2[n][k], acc[m][n + 2], 0, 0, 0);
            __builtin_amdgcn_s_setprio(0);
        }
        if (st) { PROC(q1, dstA, oHi, ps1); ISSUE(q3, g3, koff); SB0(); }

        // ---- phase 2: A m4-7; 16 MFMA (reuse bv2) ----
        {
#pragma unroll
            for (int m = 0; m < 4; ++m) {
                av[m][0] = *(const short8*)(Ab + (m + 4) * 2048 + cof0);
                av[m][1] = *(const short8*)(Ab + (m + 4) * 2048 + cof1);
            }
            __builtin_amdgcn_s_setprio(1);
#pragma unroll
            for (int k = 0; k < 2; ++k)
#pragma unroll
                for (int m = 0; m < 4; ++m)
#pragma unroll
                    for (int n = 0; n < 2; ++n)
                        acc[m + 4][n + 2] = __builtin_amdgcn_mfma_f32_16x16x32_bf16(av[m][k], bv2[n][k], acc[m + 4][n + 2], 0, 0, 0);
            __builtin_amdgcn_s_setprio(0);
        }
        if (st) PROC(q2, dstB, oLo, ps2);

        // ---- phase 3: B n0-1 re-read; 16 MFMA ----
        {
            short8 bv[2][2];
#pragma unroll
            for (int n = 0; n < 2; ++n) {
                bv[n][0] = *(const short8*)(Bb + n * 2048 + cof0);
                bv[n][1] = *(const short8*)(Bb + n * 2048 + cof1);
            }
            __builtin_amdgcn_s_setprio(1);
#pragma unroll
            for (int k = 0; k < 2; ++k)
#pragma unroll
                for (int m = 0; m < 4; ++m)
#pragma unroll
                    for (int n = 0; n < 2; ++n)
                        acc[m + 4][n] = __builtin_amdgcn_mfma_f32_16x16x32_bf16(av[m][k], bv[n][k], acc[m + 4][n], 0, 0, 0);
            __builtin_amdgcn_s_setprio(0);
        }
        if (st) PROC(q3, dstB, oHi, ps3);

        if (kt < 6) {   // cross-barrier prefetch of next iteration's first half
            const int koff2 = (kt + 2) * 64;
            ISSUE(q0, g0, koff2); ISSUE(q1, g1, koff2); SB0();
        }

        __syncthreads();   // writes to buf^1 committed; reads of buf done
    }

    // ---- norm reduce: quad shuffle + single LDS write ----
    ps0 += __shfl_xor(ps0, 1, 64); ps0 += __shfl_xor(ps0, 2, 64);
    ps1 += __shfl_xor(ps1, 1, 64); ps1 += __shfl_xor(ps1, 2, 64);
    ps2 += __shfl_xor(ps2, 1, 64); ps2 += __shfl_xor(ps2, 2, 64);
    ps3 += __shfl_xor(ps3, 1, 64); ps3 += __shfl_xor(ps3, 2, 64);
    if (lq == 0) {
        lnrm[rg]       = ps0;
        lnrm[128 + rg] = ps1;
        lnrm[256 + rg] = ps2;
        lnrm[384 + rg] = ps3;
    }
    __syncthreads();

    // ---- fused epilogue: out = sqrt(max(||a||^2 + ||v||^2 - 2*cross, 0)) ----
    float* Ob = out + (size_t)b * A_ * V_ + (size_t)(ab * 256) * V_ + vb * 256;
#pragma unroll
    for (int m = 0; m < 8; ++m) {
#pragma unroll
        for (int n = 0; n < 4; ++n) {
            const int col = wn * 64 + n * 16 + frow;      // C/D: col = lane&15
            const float vsq = lnrm[256 + col];
#pragma unroll
            for (int j = 0; j < 4; ++j) {
                const int row = wm * 128 + m * 16 + fg * 4 + j;   // row=(lane>>4)*4+reg
                float d2 = lnrm[row] + vsq - 2.f * acc[m][n][j];
                Ob[(size_t)row * V_ + col] = sqrtf(fmaxf(d2, 0.f));
            }
        }
    }
#undef ISSUE
#undef PROC
}

extern "C" void kernel_launch(void* const* d_in, const int* in_sizes, int n_in,
                              void* d_out, int out_size, void* d_ws, size_t ws_size,
                              hipStream_t stream) {
    const float* audio  = (const float*)d_in[0];
    const float* visual = (const float*)d_in[1];
    float* out = (float*)d_out;
    l2dist_fused256<<<256, 512, 0, stream>>>(audio, visual, out);
}

// Round 6
// 49.049 us; speedup vs baseline: 1.0024x; 1.0024x over previous
//
#include <hip/hip_runtime.h>
#include <hip/hip_bf16.h>

typedef __attribute__((ext_vector_type(8))) short short8;   // 8 bf16 MFMA A/B frag
typedef __attribute__((ext_vector_type(4))) float fv4;      // MFMA C/D frag

constexpr int B_ = 16, A_ = 1024, V_ = 1024, D_ = 512;

__device__ __forceinline__ unsigned cvtpk(float lo, float hi) {
    unsigned r;
    asm("v_cvt_pk_bf16_f32 %0, %1, %2" : "=v"(r) : "v"(lo), "v"(hi));
    return r;
}
#define SB0() __builtin_amdgcn_sched_barrier(0)
// Barrier that drains ONLY LDS (lgkmcnt) — global register loads stay in
// flight across it (the whole point of the cross-barrier prefetch). The
// "memory" clobber pins LDS reads/writes on their side of the barrier.
#define BARX() asm volatile("s_waitcnt lgkmcnt(0)\n\ts_barrier" ::: "memory")

struct Stage { fv4 x0, x1, x2, x3; };

// Fused: fp32 -> bf16 convert + row norms + 256x256 MFMA tile + sqrt epilogue.
// 512 threads = 8 waves (2M x 4N). BK=64, 8 K-tiles, double-buffered LDS.
// Staging loads for the NEXT tile are issued one tile-boundary early and
// survive the (lgkm-only) barrier; norms accumulate in registers.
__global__ void __launch_bounds__(512, 2)
l2dist_fused256(const float* __restrict__ audio, const float* __restrict__ visual,
                float* __restrict__ out)
{
    __shared__ __align__(16) char sA[2 * 256 * 128];   // [buf][row 256][64 bf16]
    __shared__ __align__(16) char sB[2 * 256 * 128];
    __shared__ float lnrm[512];                        // [0..255]=A rows, [256..511]=V rows

    const int t = threadIdx.x, lane = t & 63, w = t >> 6;
    const int wm = w >> 2, wn = w & 3;                 // wave C-slab: 128 rows x 64 cols

    // XCD-bijective swizzle: 256 blocks; each XCD gets 32 = 2 whole batches.
    const int orig = blockIdx.x;
    const int wg   = (orig & 7) * 32 + (orig >> 3);
    const int b = wg >> 4, tile = wg & 15, ab = tile >> 2, vb = tile & 3;

    const float* Ag = audio  + ((size_t)b * A_ + ab * 256) * D_;
    const float* Vg = visual + ((size_t)b * V_ + vb * 256) * D_;

    // staging geometry: 4-lane quad per row; thread covers 16 floats of one row
    const int rg  = t >> 2;            // 0..127 row within half-panel
    const int lq  = t & 3;             // quad lane
    const int key = rg & 7;            // LDS chunk swizzle key

    const float* g0 = Ag + (size_t)rg * D_ + lq * 4;           // A rows 0-127
    const float* g1 = Ag + (size_t)(128 + rg) * D_ + lq * 4;   // A rows 128-255
    const float* g2 = Vg + (size_t)rg * D_ + lq * 4;           // V rows 0-127
    const float* g3 = Vg + (size_t)(128 + rg) * D_ + lq * 4;   // V rows 128-255

    const int oLo = rg * 128;                // LDS row byte offset, half 0
    const int oHi = (128 + rg) * 128;        // half 1

    float ps0 = 0.f, ps1 = 0.f, ps2 = 0.f, ps3 = 0.f;   // register norm partials

#define ISSUE(S, gbase, koff) do {                                   \
        const float* _p = (gbase) + (koff);                          \
        S.x0 = *(const fv4*)(_p);      S.x1 = *(const fv4*)(_p + 16);\
        S.x2 = *(const fv4*)(_p + 32); S.x3 = *(const fv4*)(_p + 48);\
    } while (0)

    // convert + fp32 norm partial + swizzled LDS write for one quarter
#define PROC(S, dst, rowoff, ps) do {                                            \
        ps += S.x0[0]*S.x0[0] + S.x0[1]*S.x0[1] + S.x0[2]*S.x0[2] + S.x0[3]*S.x0[3] \
            + S.x1[0]*S.x1[0] + S.x1[1]*S.x1[1] + S.x1[2]*S.x1[2] + S.x1[3]*S.x1[3] \
            + S.x2[0]*S.x2[0] + S.x2[1]*S.x2[1] + S.x2[2]*S.x2[2] + S.x2[3]*S.x2[3] \
            + S.x3[0]*S.x3[0] + S.x3[1]*S.x3[1] + S.x3[2]*S.x3[2] + S.x3[3]*S.x3[3];\
        char* _d = (dst) + (rowoff);                                             \
        { int2 _v; _v.x = (int)cvtpk(S.x0[0], S.x0[1]); _v.y = (int)cvtpk(S.x0[2], S.x0[3]); \
          *(int2*)(_d + ((((0 + (lq >> 1)) ^ key) << 4) + (lq & 1) * 8)) = _v; } \
        { int2 _v; _v.x = (int)cvtpk(S.x1[0], S.x1[1]); _v.y = (int)cvtpk(S.x1[2], S.x1[3]); \
          *(int2*)(_d + ((((2 + (lq >> 1)) ^ key) << 4) + (lq & 1) * 8)) = _v; } \
        { int2 _v; _v.x = (int)cvtpk(S.x2[0], S.x2[1]); _v.y = (int)cvtpk(S.x2[2], S.x2[3]); \
          *(int2*)(_d + ((((4 + (lq >> 1)) ^ key) << 4) + (lq & 1) * 8)) = _v; } \
        { int2 _v; _v.x = (int)cvtpk(S.x3[0], S.x3[1]); _v.y = (int)cvtpk(S.x3[2], S.x3[3]); \
          *(int2*)(_d + ((((6 + (lq >> 1)) ^ key) << 4) + (lq & 1) * 8)) = _v; } \
    } while (0)

    // ---- prologue: stage K-tile 0 into buf 0; prefetch q0,q1 of K-tile 1 ----
    Stage q0, q1, q2, q3;
    {
        Stage p0, p1, p2, p3;
        ISSUE(p0, g0, 0); ISSUE(p1, g1, 0); ISSUE(p2, g2, 0); ISSUE(p3, g3, 0); SB0();
        PROC(p0, sA, oLo, ps0);
        PROC(p1, sA, oHi, ps1);
        PROC(p2, sB, oLo, ps2);
        PROC(p3, sB, oHi, ps3);
    }
    ISSUE(q0, g0, 64); ISSUE(q1, g1, 64); SB0();   // survives the lgkm-only barrier
    BARX();

    fv4 acc[8][4];
#pragma unroll
    for (int m = 0; m < 8; ++m)
#pragma unroll
        for (int n = 0; n < 4; ++n) acc[m][n] = fv4{0.f, 0.f, 0.f, 0.f};

    const int frow = lane & 15, fg = lane >> 4, xk = frow & 7;
    const int cof0 = ((0 + fg) ^ xk) << 4;    // k-half 0 swizzled chunk
    const int cof1 = ((4 + fg) ^ xk) << 4;    // k-half 1

#pragma unroll 1
    for (int kt = 0; kt < 8; ++kt) {
        const int cur = kt & 1;
        char* dstA = sA + (cur ^ 1) * 32768;
        char* dstB = sB + (cur ^ 1) * 32768;
        const char* Ab = sA + cur * 32768 + (wm * 128 + frow) * 128;
        const char* Bb = sB + cur * 32768 + (wn * 64 + frow) * 128;
        const int koff = (kt + 1) * 64;       // data staged THIS iteration
        const bool st = (kt < 7);

        short8 av[4][2];
        // ---- phase 0: A m0-3, B n0-1; 16 MFMA ----
        {
            short8 bv[2][2];
#pragma unroll
            for (int m = 0; m < 4; ++m) {
                av[m][0] = *(const short8*)(Ab + m * 2048 + cof0);
                av[m][1] = *(const short8*)(Ab + m * 2048 + cof1);
            }
#pragma unroll
            for (int n = 0; n < 2; ++n) {
                bv[n][0] = *(const short8*)(Bb + n * 2048 + cof0);
                bv[n][1] = *(const short8*)(Bb + n * 2048 + cof1);
            }
            __builtin_amdgcn_s_setprio(1);
#pragma unroll
            for (int k = 0; k < 2; ++k)
#pragma unroll
                for (int m = 0; m < 4; ++m)
#pragma unroll
                    for (int n = 0; n < 2; ++n)
                        acc[m][n] = __builtin_amdgcn_mfma_f32_16x16x32_bf16(av[m][k], bv[n][k], acc[m][n], 0, 0, 0);
            __builtin_amdgcn_s_setprio(0);
        }
        if (st) { PROC(q0, dstA, oLo, ps0); ISSUE(q2, g2, koff); SB0(); }

        // ---- phase 1: B n2-3; 16 MFMA (reuse av) ----
        short8 bv2[2][2];
        {
#pragma unroll
            for (int n = 0; n < 2; ++n) {
                bv2[n][0] = *(const short8*)(Bb + (n + 2) * 2048 + cof0);
                bv2[n][1] = *(const short8*)(Bb + (n + 2) * 2048 + cof1);
            }
            __builtin_amdgcn_s_setprio(1);
#pragma unroll
            for (int k = 0; k < 2; ++k)
#pragma unroll
                for (int m = 0; m < 4; ++m)
#pragma unroll
                    for (int n = 0; n < 2; ++n)
                        acc[m][n + 2] = __builtin_amdgcn_mfma_f32_16x16x32_bf16(av[m][k], bv2[n][k], acc[m][n + 2], 0, 0, 0);
            __builtin_amdgcn_s_setprio(0);
        }
        if (st) { PROC(q1, dstA, oHi, ps1); ISSUE(q3, g3, koff); SB0(); }

        // ---- phase 2: A m4-7; 16 MFMA (reuse bv2) ----
        {
#pragma unroll
            for (int m = 0; m < 4; ++m) {
                av[m][0] = *(const short8*)(Ab + (m + 4) * 2048 + cof0);
                av[m][1] = *(const short8*)(Ab + (m + 4) * 2048 + cof1);
            }
            __builtin_amdgcn_s_setprio(1);
#pragma unroll
            for (int k = 0; k < 2; ++k)
#pragma unroll
                for (int m = 0; m < 4; ++m)
#pragma unroll
                    for (int n = 0; n < 2; ++n)
                        acc[m + 4][n + 2] = __builtin_amdgcn_mfma_f32_16x16x32_bf16(av[m][k], bv2[n][k], acc[m + 4][n + 2], 0, 0, 0);
            __builtin_amdgcn_s_setprio(0);
        }
        if (st) PROC(q2, dstB, oLo, ps2);

        // ---- phase 3: B n0-1 re-read; 16 MFMA ----
        {
            short8 bv[2][2];
#pragma unroll
            for (int n = 0; n < 2; ++n) {
                bv[n][0] = *(const short8*)(Bb + n * 2048 + cof0);
                bv[n][1] = *(const short8*)(Bb + n * 2048 + cof1);
            }
            __builtin_amdgcn_s_setprio(1);
#pragma unroll
            for (int k = 0; k < 2; ++k)
#pragma unroll
                for (int m = 0; m < 4; ++m)
#pragma unroll
                    for (int n = 0; n < 2; ++n)
                        acc[m + 4][n] = __builtin_amdgcn_mfma_f32_16x16x32_bf16(av[m][k], bv[n][k], acc[m + 4][n], 0, 0, 0);
            __builtin_amdgcn_s_setprio(0);
        }
        if (st) PROC(q3, dstB, oHi, ps3);

        if (kt < 6) {   // cross-barrier prefetch of next iteration's first half
            const int koff2 = (kt + 2) * 64;
            ISSUE(q0, g0, koff2); ISSUE(q1, g1, koff2); SB0();
        }

        BARX();   // LDS drained + barrier; global prefetch stays in flight
    }

    // ---- norm reduce: quad shuffle + single LDS write ----
    ps0 += __shfl_xor(ps0, 1, 64); ps0 += __shfl_xor(ps0, 2, 64);
    ps1 += __shfl_xor(ps1, 1, 64); ps1 += __shfl_xor(ps1, 2, 64);
    ps2 += __shfl_xor(ps2, 1, 64); ps2 += __shfl_xor(ps2, 2, 64);
    ps3 += __shfl_xor(ps3, 1, 64); ps3 += __shfl_xor(ps3, 2, 64);
    if (lq == 0) {
        lnrm[rg]       = ps0;
        lnrm[128 + rg] = ps1;
        lnrm[256 + rg] = ps2;
        lnrm[384 + rg] = ps3;
    }
    __syncthreads();

    // ---- fused epilogue: out = sqrt(max(||a||^2 + ||v||^2 - 2*cross, 0)) ----
    float* Ob = out + (size_t)b * A_ * V_ + (size_t)(ab * 256) * V_ + vb * 256;
#pragma unroll
    for (int m = 0; m < 8; ++m) {
#pragma unroll
        for (int n = 0; n < 4; ++n) {
            const int col = wn * 64 + n * 16 + frow;      // C/D: col = lane&15
            const float vsq = lnrm[256 + col];
#pragma unroll
            for (int j = 0; j < 4; ++j) {
                const int row = wm * 128 + m * 16 + fg * 4 + j;   // row=(lane>>4)*4+reg
                float d2 = lnrm[row] + vsq - 2.f * acc[m][n][j];
                Ob[(size_t)row * V_ + col] = sqrtf(fmaxf(d2, 0.f));
            }
        }
    }
#undef ISSUE
#undef PROC
}

extern "C" void kernel_launch(void* const* d_in, const int* in_sizes, int n_in,
                              void* d_out, int out_size, void* d_ws, size_t ws_size,
                              hipStream_t stream) {
    const float* audio  = (const float*)d_in[0];
    const float* visual = (const float*)d_in[1];
    float* out = (float*)d_out;
    l2dist_fused256<<<256, 512, 0, stream>>>(audio, visual, out);
}

// Round 7
// 48.455 us; speedup vs baseline: 1.0147x; 1.0123x over previous
//
#include <hip/hip_runtime.h>
#include <hip/hip_bf16.h>

typedef __attribute__((ext_vector_type(8))) short short8;   // 8 bf16 MFMA A/B frag
typedef __attribute__((ext_vector_type(4))) float fv4;      // MFMA C/D frag

constexpr int B_ = 16, A_ = 1024, V_ = 1024, D_ = 512;

__device__ __forceinline__ unsigned cvtpk(float lo, float hi) {
    unsigned r;
    asm("v_cvt_pk_bf16_f32 %0, %1, %2" : "=v"(r) : "v"(lo), "v"(hi));
    return r;
}
__device__ __forceinline__ unsigned lds_addr(const void* p) {
    return (unsigned)(unsigned long long)(__attribute__((address_space(3))) const char*)p;
}
__device__ __forceinline__ short8 dsr128(unsigned a) {
    short8 r;
    asm volatile("ds_read_b128 %0, %1" : "=v"(r) : "v"(a));
    return r;
}
#define SB0()  __builtin_amdgcn_sched_barrier(0)
#define LGK0() asm volatile("s_waitcnt lgkmcnt(0)")
// lgkm-only barrier: per-wave LDS ops drained (covers ds_write RAW and
// ds_read WAR), then raw barrier. NO memory clobber -> no forced vmcnt drain.
#define BARX() do { SB0(); LGK0(); __builtin_amdgcn_s_barrier(); SB0(); } while (0)

struct Stage { fv4 x0, x1, x2, x3; };

// Fused: fp32->bf16 convert + row norms + 128x128 MFMA tile + sqrt epilogue.
// 256 threads = 4 waves (2M x 2N, 64x64 slabs). BK=64, 8 K-tiles, dbuf LDS.
// 2 blocks/CU: independent blocks overlap each other's stalls and epilogue.
__global__ void __launch_bounds__(256, 2)
l2dist_fused128(const float* __restrict__ audio, const float* __restrict__ visual,
                float* __restrict__ out)
{
    __shared__ __align__(16) char sA[2][128 * 128];   // [buf][row 128][64 bf16]
    __shared__ __align__(16) char sB[2][128 * 128];
    __shared__ float lnrm[256];                       // [0..127]=A rows, [128..255]=V rows

    const int t = threadIdx.x, lane = t & 63, w = t >> 6;
    const int wm = w >> 1, wn = w & 1;                // wave C-slab: 64 rows x 64 cols

    // XCD-bijective swizzle: 1024 blocks; each XCD gets 128 contiguous = 2 batches.
    const int orig = blockIdx.x;
    const int wg   = (orig & 7) * 128 + (orig >> 3);
    const int b = wg >> 6, tile = wg & 63, ab = tile >> 3, vb = tile & 7;

    const float* Ag = audio  + ((size_t)b * A_ + ab * 128) * D_;
    const float* Vg = visual + ((size_t)b * V_ + vb * 128) * D_;

    // staging geometry: 4-lane quad per row; thread covers 16 floats of one row
    const int rg  = t >> 2;            // 0..63 row within half-panel
    const int lq  = t & 3;             // quad lane
    const int key = rg & 7;            // LDS chunk swizzle key

    const float* g0 = Ag + (size_t)rg * D_ + lq * 4;          // A rows 0-63
    const float* g1 = Ag + (size_t)(64 + rg) * D_ + lq * 4;   // A rows 64-127
    const float* g2 = Vg + (size_t)rg * D_ + lq * 4;          // V rows 0-63
    const float* g3 = Vg + (size_t)(64 + rg) * D_ + lq * 4;   // V rows 64-127

    const int oLo = rg * 128;                // LDS row byte offset, half 0
    const int oHi = (64 + rg) * 128;         // half 1

    float ps0 = 0.f, ps1 = 0.f, ps2 = 0.f, ps3 = 0.f;   // register norm partials

#define ISSUE(S, gbase, koff) do {                                   \
        const float* _p = (gbase) + (koff);                          \
        S.x0 = *(const fv4*)(_p);      S.x1 = *(const fv4*)(_p + 16);\
        S.x2 = *(const fv4*)(_p + 32); S.x3 = *(const fv4*)(_p + 48);\
    } while (0)

    // convert + fp32 norm partial + swizzled LDS write for one quarter
#define PROC(S, dst, rowoff, ps) do {                                            \
        ps += S.x0[0]*S.x0[0] + S.x0[1]*S.x0[1] + S.x0[2]*S.x0[2] + S.x0[3]*S.x0[3] \
            + S.x1[0]*S.x1[0] + S.x1[1]*S.x1[1] + S.x1[2]*S.x1[2] + S.x1[3]*S.x1[3] \
            + S.x2[0]*S.x2[0] + S.x2[1]*S.x2[1] + S.x2[2]*S.x2[2] + S.x2[3]*S.x2[3] \
            + S.x3[0]*S.x3[0] + S.x3[1]*S.x3[1] + S.x3[2]*S.x3[2] + S.x3[3]*S.x3[3];\
        char* _d = (dst) + (rowoff);                                             \
        { int2 _v; _v.x = (int)cvtpk(S.x0[0], S.x0[1]); _v.y = (int)cvtpk(S.x0[2], S.x0[3]); \
          *(int2*)(_d + ((((0 + (lq >> 1)) ^ key) << 4) + (lq & 1) * 8)) = _v; } \
        { int2 _v; _v.x = (int)cvtpk(S.x1[0], S.x1[1]); _v.y = (int)cvtpk(S.x1[2], S.x1[3]); \
          *(int2*)(_d + ((((2 + (lq >> 1)) ^ key) << 4) + (lq & 1) * 8)) = _v; } \
        { int2 _v; _v.x = (int)cvtpk(S.x2[0], S.x2[1]); _v.y = (int)cvtpk(S.x2[2], S.x2[3]); \
          *(int2*)(_d + ((((4 + (lq >> 1)) ^ key) << 4) + (lq & 1) * 8)) = _v; } \
        { int2 _v; _v.x = (int)cvtpk(S.x3[0], S.x3[1]); _v.y = (int)cvtpk(S.x3[2], S.x3[3]); \
          *(int2*)(_d + ((((6 + (lq >> 1)) ^ key) << 4) + (lq & 1) * 8)) = _v; } \
    } while (0)

    // ---- prologue: stage K-tile 0 into buf 0 ----
    {
        Stage p0, p1, p2, p3;
        ISSUE(p0, g0, 0); ISSUE(p1, g1, 0); ISSUE(p2, g2, 0); ISSUE(p3, g3, 0); SB0();
        PROC(p0, (char*)sA[0], oLo, ps0);
        PROC(p1, (char*)sA[0], oHi, ps1);
        PROC(p2, (char*)sB[0], oLo, ps2);
        PROC(p3, (char*)sB[0], oHi, ps3);
    }
    __syncthreads();

    fv4 acc[4][4];
#pragma unroll
    for (int m = 0; m < 4; ++m)
#pragma unroll
        for (int n = 0; n < 4; ++n) acc[m][n] = fv4{0.f, 0.f, 0.f, 0.f};

    const int frow = lane & 15, fg = lane >> 4, xk = frow & 7;
    const unsigned cof0 = (unsigned)(((0 + fg) ^ xk) << 4);   // k-half 0 chunk
    const unsigned cof1 = (unsigned)(((4 + fg) ^ xk) << 4);   // k-half 1
    const unsigned baseA = lds_addr(&sA[0][0]);
    const unsigned baseB = lds_addr(&sB[0][0]);
    const unsigned arow = (unsigned)((wm * 64 + frow) * 128);
    const unsigned brow = (unsigned)((wn * 64 + frow) * 128);

#pragma unroll 1
    for (int kt = 0; kt < 8; ++kt) {
        const int cur = kt & 1;
        char* dA = (char*)sA[cur ^ 1];
        char* dB = (char*)sB[cur ^ 1];
        const unsigned Ab = baseA + (unsigned)cur * 16384u + arow;
        const unsigned Bb = baseB + (unsigned)cur * 16384u + brow;
        const int koff = (kt + 1) * 64;
        const bool st = (kt < 7);

        // issue next tile's global loads at iter top (max in-iter cover)
        Stage q0, q1, q2, q3;
        if (st) { ISSUE(q0, g0, koff); ISSUE(q1, g1, koff);
                  ISSUE(q2, g2, koff); ISSUE(q3, g3, koff); SB0(); }

        short8 av[4][2];
        // ---- phase 0: A m0-3 (8 reads), B n0-1 (4 reads); 16 MFMA ----
        {
            short8 bv[2][2];
#pragma unroll
            for (int m = 0; m < 4; ++m) {
                av[m][0] = dsr128(Ab + m * 2048 + cof0);
                av[m][1] = dsr128(Ab + m * 2048 + cof1);
            }
#pragma unroll
            for (int n = 0; n < 2; ++n) {
                bv[n][0] = dsr128(Bb + n * 2048 + cof0);
                bv[n][1] = dsr128(Bb + n * 2048 + cof1);
            }
            LGK0(); SB0();
            __builtin_amdgcn_s_setprio(1);
#pragma unroll
            for (int k = 0; k < 2; ++k)
#pragma unroll
                for (int m = 0; m < 4; ++m)
#pragma unroll
                    for (int n = 0; n < 2; ++n)
                        acc[m][n] = __builtin_amdgcn_mfma_f32_16x16x32_bf16(av[m][k], bv[n][k], acc[m][n], 0, 0, 0);
            __builtin_amdgcn_s_setprio(0);
        }
        if (st) { PROC(q0, dA, oLo, ps0); PROC(q1, dA, oHi, ps1); }

        // ---- phase 1: B n2-3 (4 reads); 16 MFMA (reuse av) ----
        {
            short8 bv[2][2];
#pragma unroll
            for (int n = 0; n < 2; ++n) {
                bv[n][0] = dsr128(Bb + (n + 2) * 2048 + cof0);
                bv[n][1] = dsr128(Bb + (n + 2) * 2048 + cof1);
            }
            LGK0(); SB0();
            __builtin_amdgcn_s_setprio(1);
#pragma unroll
            for (int k = 0; k < 2; ++k)
#pragma unroll
                for (int m = 0; m < 4; ++m)
#pragma unroll
                    for (int n = 0; n < 2; ++n)
                        acc[m][n + 2] = __builtin_amdgcn_mfma_f32_16x16x32_bf16(av[m][k], bv[n][k], acc[m][n + 2], 0, 0, 0);
            __builtin_amdgcn_s_setprio(0);
        }
        if (st) { PROC(q2, dB, oLo, ps2); PROC(q3, dB, oHi, ps3); }

        BARX();   // lgkm drained per-wave + raw barrier (no vmcnt drain)
    }

    // ---- norm reduce: quad shuffle + single LDS write ----
    ps0 += __shfl_xor(ps0, 1, 64); ps0 += __shfl_xor(ps0, 2, 64);
    ps1 += __shfl_xor(ps1, 1, 64); ps1 += __shfl_xor(ps1, 2, 64);
    ps2 += __shfl_xor(ps2, 1, 64); ps2 += __shfl_xor(ps2, 2, 64);
    ps3 += __shfl_xor(ps3, 1, 64); ps3 += __shfl_xor(ps3, 2, 64);
    if (lq == 0) {
        lnrm[rg]       = ps0;
        lnrm[64 + rg]  = ps1;
        lnrm[128 + rg] = ps2;
        lnrm[192 + rg] = ps3;
    }
    __syncthreads();

    // ---- fused epilogue: out = sqrt(max(||a||^2 + ||v||^2 - 2*cross, 0)) ----
    float* Ob = out + (size_t)b * A_ * V_ + (size_t)(ab * 128) * V_ + vb * 128;
#pragma unroll
    for (int m = 0; m < 4; ++m) {
#pragma unroll
        for (int n = 0; n < 4; ++n) {
            const int col = wn * 64 + n * 16 + frow;      // C/D: col = lane&15
            const float vsq = lnrm[128 + col];
#pragma unroll
            for (int j = 0; j < 4; ++j) {
                const int row = wm * 64 + m * 16 + fg * 4 + j;   // row=(lane>>4)*4+reg
                float d2 = lnrm[row] + vsq - 2.f * acc[m][n][j];
                Ob[(size_t)row * V_ + col] = sqrtf(fmaxf(d2, 0.f));
            }
        }
    }
#undef ISSUE
#undef PROC
}

extern "C" void kernel_launch(void* const* d_in, const int* in_sizes, int n_in,
                              void* d_out, int out_size, void* d_ws, size_t ws_size,
                              hipStream_t stream) {
    const float* audio  = (const float*)d_in[0];
    const float* visual = (const float*)d_in[1];
    float* out = (float*)d_out;
    l2dist_fused128<<<1024, 256, 0, stream>>>(audio, visual, out);
}